// Round 6
// baseline (329.268 us; speedup 1.0000x reference)
//
#include <hip/hip_runtime.h>
#include <math.h>

#define BB 32
#define NN 1024
#define FF 10
#define DD 64
#define MM 4
#define RR 8
#define KK 20
#define BNROWS (BB*NN)   // 32768

// ---- workspace layout (float offsets) ----
#define OFF_HIT   0ull           // h_it   [B,N,D]  2097152
#define OFF_XLIN  2097152ull     // x_lin  [B,N,D]  2097152
#define OFF_EIT   4194304ull     // e_it   [B,N]    32768
#define OFF_PIT   4227072ull     // pi_t   [B,M]    128
#define OFF_MIXED 4227200ull     // mixed  [B,N,D]  2097152
#define OFF_SI    6324352ull     // s_i    [B,N]    32768
#define OFF_SJ    6357120ull     // s_j    [B,N]    32768
#define OFF_GNN   7700608ull     // gnn_pre [B,N,D] 2097152
#define OFF_OUTP  9797760ull     // out_pre [B,N,D] 2097152
#define OFF_STAT  11894912ull    // stats 256 + pool num 2048 + pool den 32

__device__ __forceinline__ float wave_sum(float v) {
    #pragma unroll
    for (int off = 32; off; off >>= 1) v += __shfl_xor(v, off);
    return v;
}
__device__ __forceinline__ float wave_max(float v) {
    #pragma unroll
    for (int off = 32; off; off >>= 1) v = fmaxf(v, __shfl_xor(v, off));
    return v;
}

// ---------------- K1a: per-row h_it, x_lin, e_it (+ zero accum buffers) ----------------
__global__ __launch_bounds__(256) void k_rows(
    const float* __restrict__ data, const float* __restrict__ W_cond,
    const float* __restrict__ b_cond, const float* __restrict__ W_ap,
    const float* __restrict__ b_ap, const float* __restrict__ W_av,
    const float* __restrict__ W_gnn,
    float* __restrict__ h_it, float* __restrict__ x_lin, float* __restrict__ e_it,
    float* __restrict__ stats)
{
    if (blockIdx.x < 10) {
        int idx = blockIdx.x * 256 + threadIdx.x;
        if (idx < 2336) stats[idx] = 0.f;    // stats(256) + num(2048) + den(32)
    }
    int w = threadIdx.x >> 6, lane = threadIdx.x & 63;
    int r = blockIdx.x * 4 + w;               // row in [0, B*N)
    const float* dr = data + r * FF;
    float df[FF];
    #pragma unroll
    for (int f = 0; f < FF; f++) df[f] = dr[f];
    float h = b_cond[lane], x = 0.f;
    #pragma unroll
    for (int f = 0; f < FF; f++) {
        h = fmaf(df[f], W_cond[f * DD + lane], h);
        x = fmaf(df[f], W_gnn[f * DD + lane], x);
    }
    h_it[r * DD + lane] = h;
    x_lin[r * DD + lane] = x;
    float acc = b_ap[lane];
    #pragma unroll
    for (int e2 = 0; e2 < DD; e2++)
        acc = fmaf(__shfl(h, e2), W_ap[e2 * DD + lane], acc);
    float lr = acc > 0.f ? acc : 0.2f * acc;
    float ep = wave_sum(lr * W_av[lane]);
    if (lane == 0) e_it[r] = ep;
}

// ---------------- K1b: parallel pool partials ----------------
__global__ __launch_bounds__(256) void k_pool2(
    const float* __restrict__ e_it, const float* __restrict__ h_it,
    float* __restrict__ num, float* __restrict__ den)
{
    int w = threadIdx.x >> 6, lane = threadIdx.x & 63;
    int b = blockIdx.x >> 3, ch = blockIdx.x & 7;
    int base = b * NN + ch * 128 + w * 32;
    float acc = 0.f, dn = 0.f;
    #pragma unroll 4
    for (int i = 0; i < 32; i++) {
        float e = e_it[base + i];
        float wgt = expf(e);
        acc = fmaf(wgt, h_it[(size_t)(base + i) * DD + lane], acc);
        dn += wgt;
    }
    __shared__ float pa[4][DD];
    __shared__ float pd[4];
    pa[w][lane] = acc;
    if (lane == 0) pd[w] = dn;
    __syncthreads();
    if (w == 0) {
        float s = pa[0][lane] + pa[1][lane] + pa[2][lane] + pa[3][lane];
        atomicAdd(&num[b * DD + lane], s);
        if (lane == 0) atomicAdd(&den[b], pd[0] + pd[1] + pd[2] + pd[3]);
    }
}

// ---------------- K2: routing + h_sys normalize ----------------
__global__ void k_route(const float* __restrict__ num, const float* __restrict__ den,
                        const float* __restrict__ W_r, const float* __restrict__ b_r,
                        const float* __restrict__ gumbel,
                        float* __restrict__ h_sys, float* __restrict__ pi_soft,
                        float* __restrict__ pi_t)
{
    int tid = threadIdx.x;
    for (int i = tid; i < BB * DD; i += 256)
        h_sys[i] = num[i] / den[i >> 6];
    if (tid >= BB) return;
    int b = tid;
    float inv = 1.0f / den[b];
    float lg[MM];
    #pragma unroll
    for (int m = 0; m < MM; m++) lg[m] = b_r[m] + gumbel[b * MM + m];
    for (int d = 0; d < DD; d++) {
        float hv = num[b * DD + d] * inv;
        #pragma unroll
        for (int m = 0; m < MM; m++) lg[m] = fmaf(hv, W_r[d * MM + m], lg[m]);
    }
    float mx = fmaxf(fmaxf(lg[0], lg[1]), fmaxf(lg[2], lg[3]));
    float s = 0.f, p[MM];
    #pragma unroll
    for (int m = 0; m < MM; m++) { p[m] = expf(lg[m] - mx); s += p[m]; }
    #pragma unroll
    for (int m = 0; m < MM; m++) { p[m] /= s; pi_soft[b * MM + m] = p[m]; }
    int i1 = 0; float v1 = p[0];
    #pragma unroll
    for (int m = 1; m < MM; m++) if (p[m] > v1) { v1 = p[m]; i1 = m; }
    int i2 = -1; float v2 = -1.f;
    #pragma unroll
    for (int m = 0; m < MM; m++) if (m != i1 && p[m] > v2) { v2 = p[m]; i2 = m; }
    float norm = fmaxf(v1 + v2, 1e-12f);
    #pragma unroll
    for (int m = 0; m < MM; m++)
        pi_t[b * MM + m] = (m == i1 ? v1 : (m == i2 ? v2 : 0.f)) / norm;
}

// ---------------- K3: mixed embeddings + s_i/s_j (wave per row) ----------------
__global__ __launch_bounds__(256) void k_mixed(
    const float* __restrict__ e_base, const float* __restrict__ lr_u,
    const float* __restrict__ lr_v, const float* __restrict__ pi_t,
    const float* __restrict__ x_lin,
    const float* __restrict__ att_i, const float* __restrict__ att_j,
    const float* __restrict__ att_em_i, const float* __restrict__ att_em_j,
    float* __restrict__ mixed, float* __restrict__ s_i, float* __restrict__ s_j)
{
    int w = threadIdx.x >> 6, lane = threadIdx.x & 63;
    int r = blockIdx.x * 4 + w;
    int b = r >> 10, n = r & 1023;
    float LR[MM];
    #pragma unroll
    for (int m = 0; m < MM; m++) {
        float a = 0.f;
        #pragma unroll
        for (int rr = 0; rr < RR; rr++)
            a = fmaf(lr_u[(m * NN + n) * RR + rr], lr_v[(m * RR + rr) * DD + lane], a);
        LR[m] = a;
    }
    float eb = e_base[n * DD + lane];
    float mx = 0.f;
    #pragma unroll
    for (int m = 0; m < MM; m++) mx = fmaf(pi_t[b * MM + m], eb + LR[m], mx);
    mixed[(size_t)r * DD + lane] = mx;
    float x = x_lin[(size_t)r * DD + lane];
    float r1 = wave_sum(x * att_i[lane] + mx * att_em_i[lane]);
    float r2 = wave_sum(x * att_j[lane] + mx * att_em_j[lane]);
    if (lane == 0) { s_i[r] = r1; s_j[r] = r2; }
}

// ---------------- K4: FUSED score GEMM + top-20 selection + GAT + gnn stats ----------------
// grid: 32 b x 64 i-tiles = 2048 blocks. Block owns 16 rows; wave w owns rows w*4..+3.
// Lane l accumulates scores for j = jt*256 + l*4 + q  ->  slot s = jt*4+q, matching the
// selection layout j = (s>>2)*256 + lane*4 + (s&3). No score materialization.
__global__ __launch_bounds__(256, 4) void k_fuse(
    const float* __restrict__ mixed, const float* __restrict__ x_lin,
    const float* __restrict__ s_i, const float* __restrict__ s_j,
    const float* __restrict__ b_gnn, float* __restrict__ gnn_pre,
    float* __restrict__ stats)
{
    __shared__ float As[64 * 20];      // As[d][i], i<16 (stride 20)  5 KB
    __shared__ float Bs[32 * 260];     // Bs[d2][j], j<256 (stride 260) 33.3 KB
    __shared__ unsigned skey[4][64];   // per-wave candidate keys
    __shared__ int sjj[4][64];

    int t = threadIdx.x, w = t >> 6, lane = t & 63;
    int b = blockIdx.x >> 6, itile = blockIdx.x & 63;
    int i0 = itile * 16;
    const float* mb = mixed + (size_t)b * NN * DD;

    // stage As: 16 rows x 64 d, transposed
    {
        int row = t >> 4, q = t & 15;
        float4 v = *(const float4*)(mb + (size_t)(i0 + row) * DD + q * 4);
        As[(q * 4 + 0) * 20 + row] = v.x;
        As[(q * 4 + 1) * 20 + row] = v.y;
        As[(q * 4 + 2) * 20 + row] = v.z;
        As[(q * 4 + 3) * 20 + row] = v.w;
    }

    float acc[4][16];
    #pragma unroll
    for (int r = 0; r < 4; r++)
        #pragma unroll
        for (int s = 0; s < 16; s++) acc[r][s] = 0.f;

    #pragma unroll
    for (int jt = 0; jt < 4; jt++) {
        #pragma unroll
        for (int dh = 0; dh < 2; dh++) {
            __syncthreads();
            // stage Bs: 256 j x 32 d (half), transposed
            #pragma unroll
            for (int c = 0; c < 8; c++) {
                int id = t + c * 256;
                int j = id >> 3, q = id & 7;
                float4 v = *(const float4*)(mb + (size_t)(jt * 256 + j) * DD + dh * 32 + q * 4);
                Bs[(q * 4 + 0) * 260 + j] = v.x;
                Bs[(q * 4 + 1) * 260 + j] = v.y;
                Bs[(q * 4 + 2) * 260 + j] = v.z;
                Bs[(q * 4 + 3) * 260 + j] = v.w;
            }
            __syncthreads();
            #pragma unroll 8
            for (int d2 = 0; d2 < 32; d2++) {
                float4 a4 = *(const float4*)&As[(dh * 32 + d2) * 20 + w * 4];  // broadcast
                float4 b4 = *(const float4*)&Bs[d2 * 260 + lane * 4];
                float av[4] = {a4.x, a4.y, a4.z, a4.w};
                float bv[4] = {b4.x, b4.y, b4.z, b4.w};
                #pragma unroll
                for (int r = 0; r < 4; r++)
                    #pragma unroll
                    for (int q = 0; q < 4; q++)
                        acc[r][q + jt * 4] = fmaf(av[r], bv[q], acc[r][q + jt * 4]);
            }
        }
    }

    // ---- per-row selection + GAT (scores already in k_selgat layout) ----
    float sl = 0.f, ql = 0.f;
    #pragma unroll
    for (int r = 0; r < 4; r++) {
        int n = i0 + w * 4 + r;
        int gr = (b << 10) + n;

        unsigned uk[16];
        #pragma unroll
        for (int s = 0; s < 16; s++) {
            unsigned u = __float_as_uint(acc[r][s]);
            uk[s] = u ^ (((unsigned)((int)u >> 31)) | 0x80000000u);
        }
        unsigned mx = uk[0];
        #pragma unroll
        for (int i = 1; i < 16; i++) mx = uk[i] > mx ? uk[i] : mx;
        // bitonic sort-64 (desc) of lane maxima -> tau
        unsigned sv = mx;
        #pragma unroll
        for (int blk = 2; blk <= 64; blk <<= 1) {
            #pragma unroll
            for (int dist = blk >> 1; dist >= 1; dist >>= 1) {
                unsigned pv = (unsigned)__shfl_xor((int)sv, dist);
                bool up = (lane & blk) == 0;
                bool upper = (lane & dist) == 0;
                bool g = sv > pv;
                sv = (((g == upper) == up)) ? sv : pv;
            }
        }
        unsigned tau = (unsigned)__shfl((int)sv, 19);

        int base = 0;
        #pragma unroll
        for (int s = 0; s < 16; s++) {
            bool q = uk[s] >= tau;
            unsigned long long m = __ballot(q);
            if (q) {
                int pos = base + __popcll(m & ((1ull << lane) - 1ull));
                if (pos < 64) {
                    skey[w][pos] = uk[s];
                    sjj[w][pos] = ((s >> 2) << 8) + lane * 4 + (s & 3);
                }
            }
            base += __popcll(m);
        }
        int C = base;

        float vk = -INFINITY; int ik = 0;
        if (C <= 64) {
            unsigned ck = 0u; int cj = 0x7FFFFFFF;
            if (lane < C) { ck = skey[w][lane]; cj = sjj[w][lane]; }
            if (C <= 32) {
                #pragma unroll
                for (int blk = 2; blk <= 32; blk <<= 1)
                    #pragma unroll
                    for (int dist = blk >> 1; dist >= 1; dist >>= 1) {
                        unsigned pk = (unsigned)__shfl_xor((int)ck, dist);
                        int pj = __shfl_xor(cj, dist);
                        bool up = (lane & blk) == 0;
                        bool upper = (lane & dist) == 0;
                        bool g = (ck > pk) || (ck == pk && cj < pj);
                        bool keep = ((g == upper) == up);
                        ck = keep ? ck : pk; cj = keep ? cj : pj;
                    }
            } else {
                #pragma unroll
                for (int blk = 2; blk <= 64; blk <<= 1)
                    #pragma unroll
                    for (int dist = blk >> 1; dist >= 1; dist >>= 1) {
                        unsigned pk = (unsigned)__shfl_xor((int)ck, dist);
                        int pj = __shfl_xor(cj, dist);
                        bool up = (lane & blk) == 0;
                        bool upper = (lane & dist) == 0;
                        bool g = (ck > pk) || (ck == pk && cj < pj);
                        bool keep = ((g == upper) == up);
                        ck = keep ? ck : pk; cj = keep ? cj : pj;
                    }
            }
            if (lane < KK) {
                unsigned u = (ck & 0x80000000u) ? (ck ^ 0x80000000u) : ~ck;
                vk = __uint_as_float(u);
                ik = cj;
            }
        } else {
            for (int k = 0; k < KK; k++) {
                unsigned bm = uk[0]; int bsl = 0;
                #pragma unroll
                for (int i = 1; i < 16; i++) if (uk[i] > bm) { bm = uk[i]; bsl = i; }
                unsigned wm = bm;
                #pragma unroll
                for (int off = 32; off; off >>= 1) {
                    unsigned tt = (unsigned)__shfl_xor((int)wm, off);
                    wm = tt > wm ? tt : wm;
                }
                unsigned long long ball = __ballot(bm == wm);
                int winner = (int)__builtin_ctzll(ball);
                int slotw = __shfl(bsl, winner);
                int jw = ((slotw >> 2) << 8) + winner * 4 + (slotw & 3);
                unsigned u2 = (wm & 0x80000000u) ? (wm ^ 0x80000000u) : ~wm;
                if (lane == k) { vk = __uint_as_float(u2); ik = jw; }
                if (lane == winner) uk[bsl] = 0u;
            }
        }

        // ---- GAT ----
        float m1 = wave_max(vk);
        float ek = (lane < KK) ? expf(vk - m1) : 0.f;
        float s1v = wave_sum(ek);
        float wk = ek / s1v;
        float si = s_i[gr], sjn = s_j[gr];
        float a = -INFINITY;
        if (lane < KK) {
            float sjk = s_j[(b << 10) + ik];
            float t2 = si + sjk;
            a = (ik == n) ? -INFINITY : (t2 > 0.f ? t2 : 0.2f * t2);
        }
        float ts = si + sjn;
        float aself = ts > 0.f ? ts : 0.2f * ts;
        float am = wave_max(fmaxf(a, aself));
        float ea = (lane < KK && a != -INFINITY) ? expf(a - am) : 0.f;
        float es = expf(aself - am);
        float ssum = wave_sum(ea) + es;
        float wnb = (ea / ssum) * wk;
        float wself = es / ssum;
        float accg = b_gnn[lane] + wself * x_lin[(size_t)gr * DD + lane];
        #pragma unroll
        for (int k = 0; k < KK; k++) {
            int jk = __shfl(ik, k);
            float wv = __shfl(wnb, k);
            accg = fmaf(wv, x_lin[((size_t)(b << 10) + jk) * DD + lane], accg);
        }
        gnn_pre[(size_t)gr * DD + lane] = accg;
        sl += accg; ql = fmaf(accg, accg, ql);
    }

    // ---- block-level gnn stats (reuse As as scratch) ----
    __syncthreads();
    As[w * 64 + lane] = sl;
    As[256 + w * 64 + lane] = ql;
    __syncthreads();
    if (w == 0) {
        float S = As[lane] + As[64 + lane] + As[128 + lane] + As[192 + lane];
        float Q = As[256 + lane] + As[320 + lane] + As[384 + lane] + As[448 + lane];
        atomicAdd(&stats[lane], S);
        atomicAdd(&stats[64 + lane], Q);
    }
}

// ---------------- K7: bn1 + relu + embed multiply (+ bno stats partials) ----------------
__global__ __launch_bounds__(256) void k_bn1(
    const float* __restrict__ gnn_pre, float* __restrict__ stats,
    const float* __restrict__ gamma, const float* __restrict__ beta,
    const float* __restrict__ net, float* __restrict__ out_pre)
{
    int tid = threadIdx.x;
    int d0 = (tid & 15) * 4;
    float mean4[4], rs4[4], bt4[4];
    #pragma unroll
    for (int k = 0; k < 4; k++) {
        float mu = stats[d0 + k] * (1.0f / BNROWS);
        float var = stats[64 + d0 + k] * (1.0f / BNROWS) - mu * mu;
        mean4[k] = mu;
        rs4[k] = rsqrtf(var + 1e-5f) * gamma[d0 + k];
        bt4[k] = beta[d0 + k];
    }
    float s4[4] = {0, 0, 0, 0}, q4[4] = {0, 0, 0, 0};
    size_t base4 = (size_t)blockIdx.x * 2048;     // float4 units (128 rows/block)
    #pragma unroll
    for (int i = 0; i < 8; i++) {
        size_t f4 = base4 + (size_t)i * 256 + tid;
        float4 v = ((const float4*)gnn_pre)[f4];
        int n = ((int)(f4 >> 4)) & 1023;
        float4 nv = ((const float4*)net)[(size_t)n * 16 + (tid & 15)];
        float vv[4] = {v.x, v.y, v.z, v.w};
        float nn2[4] = {nv.x, nv.y, nv.z, nv.w};
        float ov[4];
        #pragma unroll
        for (int k = 0; k < 4; k++) {
            float y = (vv[k] - mean4[k]) * rs4[k] + bt4[k];
            y = y > 0.f ? y : 0.f;
            float o = y * nn2[k];
            ov[k] = o;
            s4[k] += o;
            q4[k] = fmaf(o, o, q4[k]);
        }
        float4 o4 = {ov[0], ov[1], ov[2], ov[3]};
        ((float4*)out_pre)[f4] = o4;
    }
    __shared__ float4 ls[256], lq[256];
    ls[tid] = make_float4(s4[0], s4[1], s4[2], s4[3]);
    lq[tid] = make_float4(q4[0], q4[1], q4[2], q4[3]);
    __syncthreads();
    if (tid < 16) {
        float4 S = ls[tid], Q = lq[tid];
        #pragma unroll
        for (int rr = 1; rr < 16; rr++) {
            float4 a = ls[tid + 16 * rr], b = lq[tid + 16 * rr];
            S.x += a.x; S.y += a.y; S.z += a.z; S.w += a.w;
            Q.x += b.x; Q.y += b.y; Q.z += b.z; Q.w += b.w;
        }
        atomicAdd(&stats[128 + tid * 4 + 0], S.x);
        atomicAdd(&stats[128 + tid * 4 + 1], S.y);
        atomicAdd(&stats[128 + tid * 4 + 2], S.z);
        atomicAdd(&stats[128 + tid * 4 + 3], S.w);
        atomicAdd(&stats[192 + tid * 4 + 0], Q.x);
        atomicAdd(&stats[192 + tid * 4 + 1], Q.y);
        atomicAdd(&stats[192 + tid * 4 + 2], Q.z);
        atomicAdd(&stats[192 + tid * 4 + 3], Q.w);
    }
}

// ---------------- K8: bn_out + relu + head ----------------
__global__ __launch_bounds__(256) void k_head(
    const float* __restrict__ out_pre, const float* __restrict__ stats,
    const float* __restrict__ gamma, const float* __restrict__ beta,
    const float* __restrict__ W_out, const float* __restrict__ b_out,
    float* __restrict__ out)
{
    int w = threadIdx.x >> 6, lane = threadIdx.x & 63;
    int r = blockIdx.x * 4 + w;
    float mean = stats[lane] * (1.0f / BNROWS);
    float var = stats[DD + lane] * (1.0f / BNROWS) - mean * mean;
    float rs = rsqrtf(var + 1e-5f);
    float y = (out_pre[(size_t)r * DD + lane] - mean) * rs * gamma[lane] + beta[lane];
    y = y > 0.f ? y : 0.f;
    float p = wave_sum(y * W_out[lane]);
    if (lane == 0) out[r] = p + b_out[0];
}

extern "C" void kernel_launch(void* const* d_in, const int* in_sizes, int n_in,
                              void* d_out, int out_size, void* d_ws, size_t ws_size,
                              hipStream_t stream)
{
    const float* data     = (const float*)d_in[0];
    const float* gumbel   = (const float*)d_in[1];
    const float* W_cond   = (const float*)d_in[2];
    const float* b_cond   = (const float*)d_in[3];
    const float* W_ap     = (const float*)d_in[4];
    const float* b_ap     = (const float*)d_in[5];
    const float* W_av     = (const float*)d_in[6];
    const float* W_r      = (const float*)d_in[7];
    const float* b_r      = (const float*)d_in[8];
    const float* e_base   = (const float*)d_in[9];
    const float* lr_u     = (const float*)d_in[10];
    const float* lr_v     = (const float*)d_in[11];
    const float* W_gnn    = (const float*)d_in[12];
    const float* att_i    = (const float*)d_in[13];
    const float* att_j    = (const float*)d_in[14];
    const float* att_em_i = (const float*)d_in[15];
    const float* att_em_j = (const float*)d_in[16];
    const float* b_gnn    = (const float*)d_in[17];
    const float* bn1_g    = (const float*)d_in[18];
    const float* bn1_b    = (const float*)d_in[19];
    const float* net      = (const float*)d_in[20];
    const float* bno_g    = (const float*)d_in[21];
    const float* bno_b    = (const float*)d_in[22];
    const float* W_out    = (const float*)d_in[23];
    const float* b_out    = (const float*)d_in[24];

    float* ws = (float*)d_ws;
    float* h_it   = ws + OFF_HIT;
    float* x_lin  = ws + OFF_XLIN;
    float* e_it   = ws + OFF_EIT;
    float* pi_t   = ws + OFF_PIT;
    float* mixed  = ws + OFF_MIXED;
    float* s_i    = ws + OFF_SI;
    float* s_j    = ws + OFF_SJ;
    float* gnn_pre = ws + OFF_GNN;
    float* out_pre = ws + OFF_OUTP;
    float* stats   = ws + OFF_STAT;          // 256 stats
    float* pnum    = stats + 256;            // 2048
    float* pden    = stats + 2304;           // 32

    float* out0    = (float*)d_out;
    float* h_sys   = out0 + BB * NN;              // 32768
    float* pi_soft = out0 + BB * NN + BB * DD;    // 34816

    k_rows<<<BNROWS / 4, 256, 0, stream>>>(data, W_cond, b_cond, W_ap, b_ap, W_av, W_gnn,
                                           h_it, x_lin, e_it, stats);
    k_pool2<<<BB * 8, 256, 0, stream>>>(e_it, h_it, pnum, pden);
    k_route<<<1, 256, 0, stream>>>(pnum, pden, W_r, b_r, gumbel, h_sys, pi_soft, pi_t);
    k_mixed<<<BNROWS / 4, 256, 0, stream>>>(e_base, lr_u, lr_v, pi_t, x_lin,
                                            att_i, att_j, att_em_i, att_em_j, mixed, s_i, s_j);
    k_fuse<<<2048, 256, 0, stream>>>(mixed, x_lin, s_i, s_j, b_gnn, gnn_pre, stats);
    k_bn1<<<256, 256, 0, stream>>>(gnn_pre, stats, bn1_g, bn1_b, net, out_pre);
    k_head<<<BNROWS / 4, 256, 0, stream>>>(out_pre, stats + 128, bno_g, bno_b, W_out, b_out, out0);
}